// Round 2
// baseline (7396.772 us; speedup 1.0000x reference)
//
#include <hip/hip_runtime.h>

// AttentionRNN: B=1024, T=256, U=256.
//  P[t][b][0:1792) = x_t[b] @ [Wemb | Wre | Wnew]   (fp16 MFMA GEMM, chunked over T)
//  per step: qg = state @ [Wsk | Wrs] (fp16 MFMA, fp32 state in LDS), then
//  scores/softmax/GRU elementwise. Recurrence independent per batch row:
//  64 blocks x 16 rows, no grid sync.

typedef unsigned short u16;
typedef _Float16 f16;
typedef _Float16 f16x8 __attribute__((ext_vector_type(8)));
typedef float f32x4 __attribute__((ext_vector_type(4)));

static __device__ __forceinline__ f32x4 mfma16(f16x8 a, f16x8 b, f32x4 c){
  return __builtin_amdgcn_mfma_f32_16x16x32_f16(a, b, c, 0, 0, 0);
}
static __device__ __forceinline__ float sigmoid_f(float x){
  return 1.0f / (1.0f + __expf(-x));
}
static __device__ __forceinline__ float tanh_f(float x){
  float e = __expf(2.0f * x);
  return 1.0f - 2.0f / (e + 1.0f);   // stable: -inf -> -1, +inf -> 1
}

// ------------- cast weights to fp16, transposed to (N x K) row-major -------------
// WcatT rows: [0,256) Wemb^T, [256,1024) Wre^T, [1024,1792) Wnew^T
// WsrT  rows: [0,256) Wsk^T, [256,1024) Wrs^T
__global__ void cast_w_kernel(const float* __restrict__ EK, const float* __restrict__ RE,
    const float* __restrict__ NW, const float* __restrict__ SK, const float* __restrict__ RS,
    f16* __restrict__ WcatT, f16* __restrict__ WsrT){
  int tid = blockIdx.x * 256 + threadIdx.x;
  if (tid < 458752){
    int n = tid >> 8, k = tid & 255;
    float v;
    if (n < 256)       v = EK[k*256 + n];
    else if (n < 1024) v = RE[k*768 + (n-256)];
    else               v = NW[k*768 + (n-1024)];
    WcatT[n*256 + k] = (f16)v;
  } else {
    int i2 = tid - 458752;
    int n = i2 >> 8, k = i2 & 255;
    float v = (n < 256) ? SK[k*256 + n] : RS[k*768 + (n-256)];
    WsrT[n*256 + k] = (f16)v;
  }
}

// ---- GEMM: C[r=tsl*1024+b][0:1792) = X[b][t_start+tsl][:] @ WcatT^T, fp16 in/out ----
__global__ __launch_bounds__(256, 2) void gemm_f16_kernel(
    const float* __restrict__ X, const f16* __restrict__ Bm,
    f16* __restrict__ C, int Mtiles, int t_start)
{
  __shared__ f16 As[128*64];
  __shared__ f16 Bs[128*64];
  const int NT = 14;                       // 1792/128
  const int nwg = Mtiles * NT;
  int bid = blockIdx.x, wg = bid;
  if ((nwg & 7) == 0){ int cpx = nwg >> 3; wg = (bid & 7) * cpx + (bid >> 3); } // XCD swizzle
  const int mt = wg / NT, nt = wg % NT;
  const int tsl = mt >> 3;                 // 8 M-tiles per time slab (1024 rows)
  const int b0  = (mt & 7) * 128;
  const int t   = t_start + tsl;
  const int n0  = nt * 128;
  const int tid = threadIdx.x;
  const int l = tid & 63, wid = tid >> 6;
  const int wr = wid >> 1, wc = wid & 1;
  const int srow = tid >> 3;               // 32 staging rows
  const int scol = (tid & 7) * 8;          // 8 elems per thread

  const size_t ASTR = 32ull * 65536ull;    // 32 b-rows, X row stride T*U=65536 floats
  const float* Ab = X + ((size_t)(b0 + srow) * 256 + t) * 256 + scol;
  const f16*   Bb = Bm + ((size_t)(n0 + srow)) * 256 + scol;

  f16x8 ra[4], rb[4];
  #pragma unroll
  for (int j = 0; j < 4; ++j){
    f32x4 v0 = *(const f32x4*)(Ab + j*ASTR);
    f32x4 v1 = *(const f32x4*)(Ab + j*ASTR + 4);
    f16x8 h;
    #pragma unroll
    for (int jj = 0; jj < 8; ++jj) h[jj] = (f16)((jj < 4) ? v0[jj] : v1[jj-4]);
    ra[j] = h;
    rb[j] = *(const f16x8*)(Bb + (size_t)j * 32 * 256);
  }

  f32x4 acc[4][4];
  #pragma unroll
  for (int mi = 0; mi < 4; ++mi)
    #pragma unroll
    for (int ni = 0; ni < 4; ++ni)
      acc[mi][ni] = (f32x4){0.f,0.f,0.f,0.f};

  for (int kt = 0; kt < 4; ++kt){
    #pragma unroll
    for (int j = 0; j < 4; ++j){           // regs -> LDS (XOR-swizzled, f16 units)
      int row = srow + j*32;
      int e = (row*64 + scol) ^ ((row & 7) << 3);
      *(f16x8*)&As[e] = ra[j];
      *(f16x8*)&Bs[e] = rb[j];
    }
    __syncthreads();
    if (kt < 3){                           // prefetch next K-tile
      #pragma unroll
      for (int j = 0; j < 4; ++j){
        f32x4 v0 = *(const f32x4*)(Ab + (kt+1)*64 + j*ASTR);
        f32x4 v1 = *(const f32x4*)(Ab + (kt+1)*64 + j*ASTR + 4);
        f16x8 h;
        #pragma unroll
        for (int jj = 0; jj < 8; ++jj) h[jj] = (f16)((jj < 4) ? v0[jj] : v1[jj-4]);
        ra[j] = h;
        rb[j] = *(const f16x8*)(Bb + (kt+1)*64 + (size_t)j * 32 * 256);
      }
    }
    #pragma unroll
    for (int kk = 0; kk < 2; ++kk){
      f16x8 af[4], bfr[4];
      #pragma unroll
      for (int mi = 0; mi < 4; ++mi){
        int row = wr*64 + mi*16 + (l & 15);
        int e = (row*64 + kk*32 + (l >> 4)*8) ^ ((row & 7) << 3);
        af[mi] = *(const f16x8*)&As[e];
      }
      #pragma unroll
      for (int ni = 0; ni < 4; ++ni){
        int row = wc*64 + ni*16 + (l & 15);
        int e = (row*64 + kk*32 + (l >> 4)*8) ^ ((row & 7) << 3);
        bfr[ni] = *(const f16x8*)&Bs[e];
      }
      #pragma unroll
      for (int mi = 0; mi < 4; ++mi)
        #pragma unroll
        for (int ni = 0; ni < 4; ++ni)
          acc[mi][ni] = mfma16(af[mi], bfr[ni], acc[mi][ni]);
    }
    __syncthreads();
  }
  const size_t m0 = (size_t)mt * 128;
  #pragma unroll
  for (int mi = 0; mi < 4; ++mi){
    #pragma unroll
    for (int ni = 0; ni < 4; ++ni){
      int col = n0 + wc*64 + ni*16 + (l & 15);
      size_t row = m0 + wr*64 + mi*16 + ((l >> 4) * 4);
      #pragma unroll
      for (int j = 0; j < 4; ++j)
        C[(row + j) * 1792 + col] = (f16)acc[mi][ni][j];
    }
  }
}

// ---------------- recurrent kernel: 64 blocks x 16 rows, 512 threads ----------------
__global__ __launch_bounds__(512, 1) void recurrent_kernel(
    const f16* __restrict__ P, const f16* __restrict__ WsrT,
    const float* __restrict__ bias, const float* __restrict__ Lk,
    float* __restrict__ state, float* __restrict__ out,
    int t0, int nsteps)
{
  __shared__ float qg[16*1028];    // [16 rows][1024 cols] padded (query | gs)
  __shared__ float stf[16*260];    // state fp32, padded (1040B = 65*16, 16B aligned)
  __shared__ float sbias[256];
  __shared__ float sL[256];
  __shared__ float sprob[16][4];

  const int tid = threadIdx.x;
  const int l = tid & 63, w = tid >> 6;          // 8 waves
  const int r0 = blockIdx.x * 16;
  const int c8 = tid & 255, rb8 = (tid >> 8) * 8;

  if (tid < 256){ sbias[tid] = bias[tid]; sL[tid] = Lk[tid]; }
  #pragma unroll
  for (int rr = 0; rr < 8; ++rr){
    int row = rb8 + rr;
    stf[row*260 + c8] = state[(size_t)(r0 + row)*256 + c8];
  }
  __syncthreads();

  const int arow = l & 15, agrp = l >> 4;

  for (int i = 0; i < nsteps; ++i){
    const int t = t0 + i;
    const bool has1 = (t >= 1), has2 = (t >= 2);

    // ---- A-fragments: fp32 state -> fp16 (lane l&15 = row, (l>>4)*8 = k base) ----
    f16x8 av[8];
    #pragma unroll
    for (int kt = 0; kt < 8; ++kt){
      const float* sp = &stf[arow*260 + kt*32 + agrp*8];
      f32x4 v0 = *(const f32x4*)sp;
      f32x4 v1 = *(const f32x4*)(sp + 4);
      f16x8 h;
      #pragma unroll
      for (int j = 0; j < 8; ++j) h[j] = (f16)((j < 4) ? v0[j] : v1[j-4]);
      av[kt] = h;
    }

    // ---- qg = state @ [Wsk|Wrs], wave w -> cols [w*128, w*128+128) ----
    #pragma unroll
    for (int nip = 0; nip < 4; ++nip){
      const int col0 = w*128 + nip*32 + arow;
      const int col1 = col0 + 16;
      const f16* wp0 = WsrT + (size_t)col0*256 + agrp*8;
      const f16* wp1 = WsrT + (size_t)col1*256 + agrp*8;
      f16x8 b0[8], b1[8];
      #pragma unroll
      for (int kt = 0; kt < 8; ++kt){ b0[kt] = *(const f16x8*)(wp0 + kt*32);
                                      b1[kt] = *(const f16x8*)(wp1 + kt*32); }
      f32x4 a0 = (f32x4){0.f,0.f,0.f,0.f}, a1 = a0;
      #pragma unroll
      for (int kt = 0; kt < 8; ++kt){
        a0 = mfma16(av[kt], b0[kt], a0);
        a1 = mfma16(av[kt], b1[kt], a1);
      }
      const int rowb = agrp * 4;
      #pragma unroll
      for (int j = 0; j < 4; ++j){
        qg[(rowb + j)*1028 + col0] = a0[j];
        qg[(rowb + j)*1028 + col1] = a1[j];
      }
    }
    __syncthreads();

    // ---- scores + softmax: wave w handles rows 2w, 2w+1 ----
    #pragma unroll
    for (int r2 = 0; r2 < 2; ++r2){
      const int row = w*2 + r2;
      const int b = r0 + row;
      float sc0 = 0.f, sc1 = 0.f, sc2 = 0.f;
      #pragma unroll
      for (int s = 0; s < 3; ++s){
        const bool have = (s == 2) || (s == 1 && has1) || (s == 0 && has2);
        const f16* Ep = P + ((size_t)(i + s)*1024 + b)*1792;
        float sum = 0.f;
        #pragma unroll
        for (int jj = 0; jj < 4; ++jj){
          int c = jj*64 + l;
          float e = have ? (float)Ep[c] : 0.f;
          sum += tanh_f(e + qg[row*1028 + c] + sbias[c]) * sL[c];
        }
        #pragma unroll
        for (int off = 32; off; off >>= 1) sum += __shfl_xor(sum, off);
        if (s == 0) sc0 = sum; else if (s == 1) sc1 = sum; else sc2 = sum;
      }
      float m = fmaxf(fmaxf(sc0, sc1), sc2);
      float e0 = __expf(sc0 - m), e1 = __expf(sc1 - m), e2 = __expf(sc2 - m);
      float inv = 1.0f / (e0 + e1 + e2);
      if (l == 0){ sprob[row][0] = e0*inv; sprob[row][1] = e1*inv; sprob[row][2] = e2*inv; }
    }
    __syncthreads();

    // ---- GRU elementwise + state update ----
    #pragma unroll
    for (int rr = 0; rr < 8; ++rr){
      const int row = rb8 + rr;
      const int b = r0 + row;
      const float p0 = sprob[row][0], p1 = sprob[row][1], p2 = sprob[row][2];
      const f16* Pm2 = P + ((size_t)(i + 0)*1024 + b)*1792;
      const f16* Pm1 = P + ((size_t)(i + 1)*1024 + b)*1792;
      const f16* Pt  = P + ((size_t)(i + 2)*1024 + b)*1792;
      float geu = p2 * (float)Pt[256 + c8];
      float ger = p2 * (float)Pt[512 + c8];
      float gec = p2 * (float)Pt[768 + c8];
      if (has1){
        geu += p1 * (float)Pm1[256 + c8];
        ger += p1 * (float)Pm1[512 + c8];
        gec += p1 * (float)Pm1[768 + c8];
      }
      if (has2){
        geu += p0 * (float)Pm2[256 + c8];
        ger += p0 * (float)Pm2[512 + c8];
        gec += p0 * (float)Pm2[768 + c8];
      }
      const float gnu = (float)Pt[1024 + c8];
      const float gnr = (float)Pt[1280 + c8];
      const float gnc = (float)Pt[1536 + c8];
      const float qq = qg[row*1028 + 256 + c8];
      const float qr = qg[row*1028 + 512 + c8];
      const float qc = qg[row*1028 + 768 + c8];
      const float up   = sigmoid_f(qq + geu + gnu);
      const float rp   = sigmoid_f(qr + ger + gnr);
      const float cand = tanh_f(rp*qc + gec + gnc);
      const float so = stf[row*260 + c8];
      const float sn = (1.0f - up)*so + up*cand;
      stf[row*260 + c8] = sn;
      if (t == 255) out[(size_t)b*256 + c8] = sn;
    }
    __syncthreads();
  }

  #pragma unroll
  for (int rr = 0; rr < 8; ++rr){
    int row = rb8 + rr;
    state[(size_t)(r0 + row)*256 + c8] = stf[row*260 + c8];
  }
}

// ---------------------------------- launch ----------------------------------
extern "C" void kernel_launch(void* const* d_in, const int* in_sizes, int n_in,
                              void* d_out, int out_size, void* d_ws, size_t ws_size,
                              hipStream_t stream)
{
  const float* X  = (const float*)d_in[0];
  const float* EK = (const float*)d_in[1];
  const float* SK = (const float*)d_in[2];
  const float* BI = (const float*)d_in[3];
  const float* LK = (const float*)d_in[4];
  const float* RS = (const float*)d_in[5];
  const float* RE = (const float*)d_in[6];
  const float* NW = (const float*)d_in[7];
  float* out = (float*)d_out;
  char* ws = (char*)d_ws;

  // workspace: P[(CT+2) slabs of 1024*1792 f16] | WcatT | WsrT | state
  const size_t slabB = 1024ull * 1792ull * 2ull;           // 3,670,016 B
  const size_t wB = 917504ull + 524288ull + 1048576ull;    // weights + state
  int CT = 4;
  if      (ws_size >= 34ull*slabB + wB) CT = 32;   // P L3-resident per chunk
  else if (ws_size >= 18ull*slabB + wB) CT = 16;
  else if (ws_size >= 10ull*slabB + wB) CT = 8;

  f16* P = (f16*)ws;
  size_t poff = (size_t)(CT + 2) * slabB;
  f16* WcatT = (f16*)(ws + poff);
  f16* WsrT  = (f16*)(ws + poff + 917504ull);
  float* state = (float*)(ws + poff + 917504ull + 524288ull);

  hipMemsetAsync(state, 0, 1048576ull, stream);
  cast_w_kernel<<<2816, 256, 0, stream>>>(EK, RE, NW, SK, RS, WcatT, WsrT);

  const int nch = 256 / CT;
  for (int c = 0; c < nch; ++c){
    const int t0 = c * CT;
    const int t_start  = (c == 0) ? 0 : (t0 - 2);
    const int slab_off = (c == 0) ? 2 : 0;
    const int Mtiles = (((c == 0) ? CT : (CT + 2)) * 1024) / 128;
    gemm_f16_kernel<<<Mtiles * 14, 256, 0, stream>>>(
        X, WcatT, P + (size_t)slab_off * 1024 * 1792, Mtiles, t_start);
    recurrent_kernel<<<64, 512, 0, stream>>>(P, WsrT, BI, LK, state, out, t0, CT);
  }
}

// Round 3
// 4475.050 us; speedup vs baseline: 1.6529x; 1.6529x over previous
//
#include <hip/hip_runtime.h>

// AttentionRNN: B=1024, T=256, U=256.
//  P[t][b][0:1792) = x_t[b] @ [Wemb | Wre | Wnew]   (fp16 MFMA GEMM, chunked over T)
//  per step: qg = state @ [Wsk | Wrs] (fp16 MFMA, fp32 state in LDS), then
//  scores/softmax/GRU elementwise. Recurrence independent per batch row:
//  64 blocks x 16 rows, no grid sync. P slabs 0,1 of chunk 0 are zeroed so the
//  t<2 "missing memory slot" cases need no branches (value rows = 0 exactly).

typedef unsigned short u16;
typedef _Float16 f16;
typedef _Float16 f16x8 __attribute__((ext_vector_type(8)));
typedef float f32x4 __attribute__((ext_vector_type(4)));

static __device__ __forceinline__ f32x4 mfma16(f16x8 a, f16x8 b, f32x4 c){
  return __builtin_amdgcn_mfma_f32_16x16x32_f16(a, b, c, 0, 0, 0);
}
static __device__ __forceinline__ float sigmoid_f(float x){
  return 1.0f / (1.0f + __expf(-x));
}
static __device__ __forceinline__ float tanh_f(float x){
  float e = __expf(2.0f * x);
  return 1.0f - 2.0f / (e + 1.0f);   // stable: -inf -> -1, +inf -> 1
}

// ------------- cast weights to fp16, transposed to (N x K) row-major -------------
__global__ void cast_w_kernel(const float* __restrict__ EK, const float* __restrict__ RE,
    const float* __restrict__ NW, const float* __restrict__ SK, const float* __restrict__ RS,
    f16* __restrict__ WcatT, f16* __restrict__ WsrT){
  int tid = blockIdx.x * 256 + threadIdx.x;
  if (tid < 458752){
    int n = tid >> 8, k = tid & 255;
    float v;
    if (n < 256)       v = EK[k*256 + n];
    else if (n < 1024) v = RE[k*768 + (n-256)];
    else               v = NW[k*768 + (n-1024)];
    WcatT[n*256 + k] = (f16)v;
  } else {
    int i2 = tid - 458752;
    int n = i2 >> 8, k = i2 & 255;
    float v = (n < 256) ? SK[k*256 + n] : RS[k*768 + (n-256)];
    WsrT[n*256 + k] = (f16)v;
  }
}

// ---- GEMM: C[r=tsl*1024+b][0:1792) = X[b][t_start+tsl][:] @ WcatT^T ----
__global__ __launch_bounds__(256, 2) void gemm_f16_kernel(
    const float* __restrict__ X, const f16* __restrict__ Bm,
    f16* __restrict__ C, int Mtiles, int t_start)
{
  __shared__ f16 As[128*64];
  __shared__ f16 Bs[128*64];
  const int NT = 14;
  const int nwg = Mtiles * NT;
  int bid = blockIdx.x, wg = bid;
  if ((nwg & 7) == 0){ int cpx = nwg >> 3; wg = (bid & 7) * cpx + (bid >> 3); }
  const int mt = wg / NT, nt = wg % NT;
  const int tsl = mt >> 3;
  const int b0  = (mt & 7) * 128;
  const int t   = t_start + tsl;
  const int n0  = nt * 128;
  const int tid = threadIdx.x;
  const int l = tid & 63, wid = tid >> 6;
  const int wr = wid >> 1, wc = wid & 1;
  const int srow = tid >> 3;
  const int scol = (tid & 7) * 8;

  const size_t ASTR = 32ull * 65536ull;
  const float* Ab = X + ((size_t)(b0 + srow) * 256 + t) * 256 + scol;
  const f16*   Bb = Bm + ((size_t)(n0 + srow)) * 256 + scol;

  f16x8 ra[4], rb[4];
  #pragma unroll
  for (int j = 0; j < 4; ++j){
    f32x4 v0 = *(const f32x4*)(Ab + j*ASTR);
    f32x4 v1 = *(const f32x4*)(Ab + j*ASTR + 4);
    f16x8 h;
    #pragma unroll
    for (int jj = 0; jj < 8; ++jj) h[jj] = (f16)((jj < 4) ? v0[jj] : v1[jj-4]);
    ra[j] = h;
    rb[j] = *(const f16x8*)(Bb + (size_t)j * 32 * 256);
  }

  f32x4 acc[4][4];
  #pragma unroll
  for (int mi = 0; mi < 4; ++mi)
    #pragma unroll
    for (int ni = 0; ni < 4; ++ni)
      acc[mi][ni] = (f32x4){0.f,0.f,0.f,0.f};

  for (int kt = 0; kt < 4; ++kt){
    #pragma unroll
    for (int j = 0; j < 4; ++j){
      int row = srow + j*32;
      int e = (row*64 + scol) ^ ((row & 7) << 3);
      *(f16x8*)&As[e] = ra[j];
      *(f16x8*)&Bs[e] = rb[j];
    }
    __syncthreads();
    if (kt < 3){
      #pragma unroll
      for (int j = 0; j < 4; ++j){
        f32x4 v0 = *(const f32x4*)(Ab + (kt+1)*64 + j*ASTR);
        f32x4 v1 = *(const f32x4*)(Ab + (kt+1)*64 + j*ASTR + 4);
        f16x8 h;
        #pragma unroll
        for (int jj = 0; jj < 8; ++jj) h[jj] = (f16)((jj < 4) ? v0[jj] : v1[jj-4]);
        ra[j] = h;
        rb[j] = *(const f16x8*)(Bb + (kt+1)*64 + (size_t)j * 32 * 256);
      }
    }
    #pragma unroll
    for (int kk = 0; kk < 2; ++kk){
      f16x8 af[4], bfr[4];
      #pragma unroll
      for (int mi = 0; mi < 4; ++mi){
        int row = wr*64 + mi*16 + (l & 15);
        int e = (row*64 + kk*32 + (l >> 4)*8) ^ ((row & 7) << 3);
        af[mi] = *(const f16x8*)&As[e];
      }
      #pragma unroll
      for (int ni = 0; ni < 4; ++ni){
        int row = wc*64 + ni*16 + (l & 15);
        int e = (row*64 + kk*32 + (l >> 4)*8) ^ ((row & 7) << 3);
        bfr[ni] = *(const f16x8*)&Bs[e];
      }
      #pragma unroll
      for (int mi = 0; mi < 4; ++mi)
        #pragma unroll
        for (int ni = 0; ni < 4; ++ni)
          acc[mi][ni] = mfma16(af[mi], bfr[ni], acc[mi][ni]);
    }
    __syncthreads();
  }
  const size_t m0 = (size_t)mt * 128;
  #pragma unroll
  for (int mi = 0; mi < 4; ++mi){
    #pragma unroll
    for (int ni = 0; ni < 4; ++ni){
      int col = n0 + wc*64 + ni*16 + (l & 15);
      size_t row = m0 + wr*64 + mi*16 + ((l >> 4) * 4);
      #pragma unroll
      for (int j = 0; j < 4; ++j)
        C[(row + j) * 1792 + col] = (f16)acc[mi][ni][j];
    }
  }
}

// ---------------- recurrent kernel: 64 blocks x 16 rows, 512 threads ----------------
__global__ __launch_bounds__(512, 1) void recurrent_kernel(
    const f16* __restrict__ P, const f16* __restrict__ WsrT,
    const float* __restrict__ bias, const float* __restrict__ Lk,
    float* __restrict__ state, float* __restrict__ out,
    int t0, int nsteps)
{
  __shared__ float qg[16*1028];     // [16 rows][1024 cols] (query | gs), padded
  __shared__ float stf[16*260];     // state fp32
  __shared__ float sprob[16][4];

  const int tid = threadIdx.x;
  const int l = tid & 63, w = tid >> 6;          // 8 waves
  const int r0 = blockIdx.x * 16;
  const int arow = l & 15, agrp = l >> 4;        // MFMA A-frag mapping

  // GRU/state mapping: one row x 8 contiguous cols per thread
  const int grow = tid >> 5;                     // 0..15
  const int gc0  = (tid & 31) * 8;               // 0..248
  const int gb   = r0 + grow;

  // scores mapping: half-wave per row
  const int srow = w*2 + (l >> 5);
  const int sb   = r0 + srow;
  const int sc0  = (l & 31) * 8;

  // per-lane score constants in registers
  const f32x4 rb0 = *(const f32x4*)(bias + sc0);
  const f32x4 rb1 = *(const f32x4*)(bias + sc0 + 4);
  const f32x4 rl0 = *(const f32x4*)(Lk + sc0);
  const f32x4 rl1 = *(const f32x4*)(Lk + sc0 + 4);

  {
    f32x4 s0 = *(const f32x4*)(state + (size_t)gb*256 + gc0);
    f32x4 s1 = *(const f32x4*)(state + (size_t)gb*256 + gc0 + 4);
    *(f32x4*)&stf[grow*260 + gc0]     = s0;
    *(f32x4*)&stf[grow*260 + gc0 + 4] = s1;
  }
  __syncthreads();

  for (int i = 0; i < nsteps; ++i){
    const int t = t0 + i;

    // ======== prefetch all P data for this step (vector loads, consumed later) ========
    const f16* P0 = P + (size_t)(i+0)*1024*1792;
    const f16* P1 = P + (size_t)(i+1)*1024*1792;
    const f16* P2 = P + (size_t)(i+2)*1024*1792;
    const f16x8 e0 = *(const f16x8*)(P0 + (size_t)sb*1792 + sc0);
    const f16x8 e1 = *(const f16x8*)(P1 + (size_t)sb*1792 + sc0);
    const f16x8 e2 = *(const f16x8*)(P2 + (size_t)sb*1792 + sc0);
    const f16* pt  = P2 + (size_t)gb*1792;
    const f16* pm1 = P1 + (size_t)gb*1792;
    const f16* pm2 = P0 + (size_t)gb*1792;
    const f16x8 gU  = *(const f16x8*)(pt  +  256 + gc0);
    const f16x8 gR  = *(const f16x8*)(pt  +  512 + gc0);
    const f16x8 gC  = *(const f16x8*)(pt  +  768 + gc0);
    const f16x8 gNU = *(const f16x8*)(pt  + 1024 + gc0);
    const f16x8 gNR = *(const f16x8*)(pt  + 1280 + gc0);
    const f16x8 gNC = *(const f16x8*)(pt  + 1536 + gc0);
    const f16x8 m1U = *(const f16x8*)(pm1 +  256 + gc0);
    const f16x8 m1R = *(const f16x8*)(pm1 +  512 + gc0);
    const f16x8 m1C = *(const f16x8*)(pm1 +  768 + gc0);
    const f16x8 m2U = *(const f16x8*)(pm2 +  256 + gc0);
    const f16x8 m2R = *(const f16x8*)(pm2 +  512 + gc0);
    const f16x8 m2C = *(const f16x8*)(pm2 +  768 + gc0);

    // ======== A-fragments: fp32 state -> fp16 ========
    f16x8 av[8];
    #pragma unroll
    for (int kt = 0; kt < 8; ++kt){
      const float* sp = &stf[arow*260 + kt*32 + agrp*8];
      f32x4 v0 = *(const f32x4*)sp;
      f32x4 v1 = *(const f32x4*)(sp + 4);
      f16x8 h;
      #pragma unroll
      for (int j = 0; j < 8; ++j) h[j] = (f16)((j < 4) ? v0[j] : v1[j-4]);
      av[kt] = h;
    }

    // ======== qg = state @ [Wsk|Wrs]; wave w -> cols [w*128, w*128+128) ========
    #pragma unroll
    for (int gp = 0; gp < 4; ++gp){
      const int colA = w*128 + gp*32 + arow;
      const f16* wpA = WsrT + (size_t)colA*256 + agrp*8;
      const f16* wpB = wpA + 16*256;
      f16x8 wA[8], wB[8];
      #pragma unroll
      for (int kt = 0; kt < 8; ++kt){
        wA[kt] = *(const f16x8*)(wpA + kt*32);
        wB[kt] = *(const f16x8*)(wpB + kt*32);
      }
      f32x4 aA0 = (f32x4){0.f,0.f,0.f,0.f}, aA1 = aA0, aB0 = aA0, aB1 = aA0;
      #pragma unroll
      for (int kt = 0; kt < 4; ++kt){          // 4 independent chains of depth 4
        aA0 = mfma16(av[2*kt],   wA[2*kt],   aA0);
        aB0 = mfma16(av[2*kt],   wB[2*kt],   aB0);
        aA1 = mfma16(av[2*kt+1], wA[2*kt+1], aA1);
        aB1 = mfma16(av[2*kt+1], wB[2*kt+1], aB1);
      }
      const int rowb = agrp * 4;
      #pragma unroll
      for (int j = 0; j < 4; ++j){
        qg[(rowb + j)*1028 + colA]      = aA0[j] + aA1[j];
        qg[(rowb + j)*1028 + colA + 16] = aB0[j] + aB1[j];
      }
    }
    __syncthreads();

    // ======== scores + softmax (half-wave per row) ========
    {
      const float* qrow = &qg[srow*1028];
      const f32x4 q0 = *(const f32x4*)(qrow + sc0);
      const f32x4 q1 = *(const f32x4*)(qrow + sc0 + 4);
      float s0 = 0.f, s1 = 0.f, s2 = 0.f;
      #pragma unroll
      for (int j = 0; j < 8; ++j){
        const float qb = ((j < 4) ? q0[j] : q1[j-4]) + ((j < 4) ? rb0[j] : rb1[j-4]);
        const float lw = (j < 4) ? rl0[j] : rl1[j-4];
        s0 += tanh_f((float)e0[j] + qb) * lw;
        s1 += tanh_f((float)e1[j] + qb) * lw;
        s2 += tanh_f((float)e2[j] + qb) * lw;
      }
      #pragma unroll
      for (int off = 16; off; off >>= 1){
        s0 += __shfl_xor(s0, off);
        s1 += __shfl_xor(s1, off);
        s2 += __shfl_xor(s2, off);
      }
      if ((l & 31) == 0){
        const float m = fmaxf(fmaxf(s0, s1), s2);
        const float x0 = __expf(s0 - m), x1 = __expf(s1 - m), x2 = __expf(s2 - m);
        const float inv = 1.0f / (x0 + x1 + x2);
        sprob[srow][0] = x0*inv; sprob[srow][1] = x1*inv; sprob[srow][2] = x2*inv;
      }
    }
    __syncthreads();

    // ======== GRU elementwise + state update (1 row x 8 cols / thread) ========
    {
      const float p0 = sprob[grow][0], p1 = sprob[grow][1], p2 = sprob[grow][2];
      const float* qrow = &qg[grow*1028];
      const f32x4 qu0 = *(const f32x4*)(qrow + 256 + gc0);
      const f32x4 qu1 = *(const f32x4*)(qrow + 256 + gc0 + 4);
      const f32x4 qr0 = *(const f32x4*)(qrow + 512 + gc0);
      const f32x4 qr1 = *(const f32x4*)(qrow + 512 + gc0 + 4);
      const f32x4 qc0 = *(const f32x4*)(qrow + 768 + gc0);
      const f32x4 qc1 = *(const f32x4*)(qrow + 768 + gc0 + 4);
      f32x4 so0 = *(const f32x4*)&stf[grow*260 + gc0];
      f32x4 so1 = *(const f32x4*)&stf[grow*260 + gc0 + 4];
      f32x4 sn0, sn1;
      #pragma unroll
      for (int j = 0; j < 8; ++j){
        const float geu = p2*(float)gU[j] + p1*(float)m1U[j] + p0*(float)m2U[j];
        const float ger = p2*(float)gR[j] + p1*(float)m1R[j] + p0*(float)m2R[j];
        const float gec = p2*(float)gC[j] + p1*(float)m1C[j] + p0*(float)m2C[j];
        const float qq = (j < 4) ? qu0[j] : qu1[j-4];
        const float qr = (j < 4) ? qr0[j] : qr1[j-4];
        const float qc = (j < 4) ? qc0[j] : qc1[j-4];
        const float up   = sigmoid_f(qq + geu + (float)gNU[j]);
        const float rp   = sigmoid_f(qr + ger + (float)gNR[j]);
        const float cand = tanh_f(rp*qc + gec + (float)gNC[j]);
        const float so = (j < 4) ? so0[j] : so1[j-4];
        const float sn = (1.0f - up)*so + up*cand;
        if (j < 4) sn0[j] = sn; else sn1[j-4] = sn;
      }
      *(f32x4*)&stf[grow*260 + gc0]     = sn0;
      *(f32x4*)&stf[grow*260 + gc0 + 4] = sn1;
      if (t == 255){
        *(f32x4*)(out + (size_t)gb*256 + gc0)     = sn0;
        *(f32x4*)(out + (size_t)gb*256 + gc0 + 4) = sn1;
      }
    }
    __syncthreads();
  }

  *(f32x4*)(state + (size_t)gb*256 + gc0)     = *(const f32x4*)&stf[grow*260 + gc0];
  *(f32x4*)(state + (size_t)gb*256 + gc0 + 4) = *(const f32x4*)&stf[grow*260 + gc0 + 4];
}

// ---------------------------------- launch ----------------------------------
extern "C" void kernel_launch(void* const* d_in, const int* in_sizes, int n_in,
                              void* d_out, int out_size, void* d_ws, size_t ws_size,
                              hipStream_t stream)
{
  const float* X  = (const float*)d_in[0];
  const float* EK = (const float*)d_in[1];
  const float* SK = (const float*)d_in[2];
  const float* BI = (const float*)d_in[3];
  const float* LK = (const float*)d_in[4];
  const float* RS = (const float*)d_in[5];
  const float* RE = (const float*)d_in[6];
  const float* NW = (const float*)d_in[7];
  float* out = (float*)d_out;
  char* ws = (char*)d_ws;

  const size_t slabB = 1024ull * 1792ull * 2ull;           // 3,670,016 B
  const size_t wB = 917504ull + 524288ull + 1048576ull;
  int CT = 4;
  if      (ws_size >= 34ull*slabB + wB) CT = 32;
  else if (ws_size >= 18ull*slabB + wB) CT = 16;
  else if (ws_size >= 10ull*slabB + wB) CT = 8;

  f16* P = (f16*)ws;
  size_t poff = (size_t)(CT + 2) * slabB;
  f16* WcatT = (f16*)(ws + poff);
  f16* WsrT  = (f16*)(ws + poff + 917504ull);
  float* state = (float*)(ws + poff + 917504ull + 524288ull);

  hipMemsetAsync(state, 0, 1048576ull, stream);
  hipMemsetAsync(P, 0, 2ull*slabB, stream);                // zero "virtual" slabs t=-2,-1
  cast_w_kernel<<<2816, 256, 0, stream>>>(EK, RE, NW, SK, RS, WcatT, WsrT);

  const int nch = 256 / CT;
  for (int c = 0; c < nch; ++c){
    const int t0 = c * CT;
    const int t_start  = (c == 0) ? 0 : (t0 - 2);
    const int slab_off = (c == 0) ? 2 : 0;
    const int Mtiles = (((c == 0) ? CT : (CT + 2)) * 1024) / 128;
    gemm_f16_kernel<<<Mtiles * 14, 256, 0, stream>>>(
        X, WcatT, P + (size_t)slab_off * 1024 * 1792, Mtiles, t_start);
    recurrent_kernel<<<64, 512, 0, stream>>>(P, WsrT, BI, LK, state, out, t0, CT);
  }
}

// Round 4
// 4029.409 us; speedup vs baseline: 1.8357x; 1.1106x over previous
//
#include <hip/hip_runtime.h>

// AttentionRNN: B=1024, T=256, U=256.
//  P[t][b][0:1792) = x_t[b] @ [Wemb | Wre | Wnew]   (fp16 MFMA GEMM, chunked over T)
//  per step: qg = state @ [Wsk | Wrs] (fp16 MFMA, fp32 state in LDS), then
//  scores/softmax/GRU elementwise. Recurrence independent per batch row:
//  64 blocks x 16 rows x 16 waves. P slabs for t=-2,-1 are zeroed (no branches).

typedef unsigned short u16;
typedef _Float16 f16;
typedef _Float16 f16x8 __attribute__((ext_vector_type(8)));
typedef _Float16 f16x4 __attribute__((ext_vector_type(4)));
typedef float f32x4 __attribute__((ext_vector_type(4)));

static __device__ __forceinline__ f32x4 mfma16(f16x8 a, f16x8 b, f32x4 c){
  return __builtin_amdgcn_mfma_f32_16x16x32_f16(a, b, c, 0, 0, 0);
}
static __device__ __forceinline__ float sigmoid_f(float x){
  return 1.0f / (1.0f + __expf(-x));
}
static __device__ __forceinline__ float tanh_f(float x){
  float e = __expf(2.0f * x);
  return 1.0f - 2.0f / (e + 1.0f);   // stable: -inf -> -1, +inf -> 1
}

// ------------- cast weights to fp16, transposed to (N x K) row-major -------------
__global__ void cast_w_kernel(const float* __restrict__ EK, const float* __restrict__ RE,
    const float* __restrict__ NW, const float* __restrict__ SK, const float* __restrict__ RS,
    f16* __restrict__ WcatT, f16* __restrict__ WsrT){
  int tid = blockIdx.x * 256 + threadIdx.x;
  if (tid < 458752){
    int n = tid >> 8, k = tid & 255;
    float v;
    if (n < 256)       v = EK[k*256 + n];
    else if (n < 1024) v = RE[k*768 + (n-256)];
    else               v = NW[k*768 + (n-1024)];
    WcatT[n*256 + k] = (f16)v;
  } else {
    int i2 = tid - 458752;
    int n = i2 >> 8, k = i2 & 255;
    float v = (n < 256) ? SK[k*256 + n] : RS[k*768 + (n-256)];
    WsrT[n*256 + k] = (f16)v;
  }
}

// ---- GEMM: C[r=tsl*1024+b][0:1792) = X[b][t_start+tsl][:] @ WcatT^T ----
__global__ __launch_bounds__(256, 2) void gemm_f16_kernel(
    const float* __restrict__ X, const f16* __restrict__ Bm,
    f16* __restrict__ C, int Mtiles, int t_start)
{
  __shared__ f16 As[128*64];
  __shared__ f16 Bs[128*64];
  const int NT = 14;
  const int nwg = Mtiles * NT;
  int bid = blockIdx.x, wg = bid;
  if ((nwg & 7) == 0){ int cpx = nwg >> 3; wg = (bid & 7) * cpx + (bid >> 3); }
  const int mt = wg / NT, nt = wg % NT;
  const int tsl = mt >> 3;
  const int b0  = (mt & 7) * 128;
  const int t   = t_start + tsl;
  const int n0  = nt * 128;
  const int tid = threadIdx.x;
  const int l = tid & 63, wid = tid >> 6;
  const int wr = wid >> 1, wc = wid & 1;
  const int srow = tid >> 3;
  const int scol = (tid & 7) * 8;

  const size_t ASTR = 32ull * 65536ull;
  const float* Ab = X + ((size_t)(b0 + srow) * 256 + t) * 256 + scol;
  const f16*   Bb = Bm + ((size_t)(n0 + srow)) * 256 + scol;

  f16x8 ra[4], rb[4];
  #pragma unroll
  for (int j = 0; j < 4; ++j){
    f32x4 v0 = *(const f32x4*)(Ab + j*ASTR);
    f32x4 v1 = *(const f32x4*)(Ab + j*ASTR + 4);
    f16x8 h;
    #pragma unroll
    for (int jj = 0; jj < 8; ++jj) h[jj] = (f16)((jj < 4) ? v0[jj] : v1[jj-4]);
    ra[j] = h;
    rb[j] = *(const f16x8*)(Bb + (size_t)j * 32 * 256);
  }

  f32x4 acc[4][4];
  #pragma unroll
  for (int mi = 0; mi < 4; ++mi)
    #pragma unroll
    for (int ni = 0; ni < 4; ++ni)
      acc[mi][ni] = (f32x4){0.f,0.f,0.f,0.f};

  for (int kt = 0; kt < 4; ++kt){
    #pragma unroll
    for (int j = 0; j < 4; ++j){
      int row = srow + j*32;
      int e = (row*64 + scol) ^ ((row & 7) << 3);
      *(f16x8*)&As[e] = ra[j];
      *(f16x8*)&Bs[e] = rb[j];
    }
    __syncthreads();
    if (kt < 3){
      #pragma unroll
      for (int j = 0; j < 4; ++j){
        f32x4 v0 = *(const f32x4*)(Ab + (kt+1)*64 + j*ASTR);
        f32x4 v1 = *(const f32x4*)(Ab + (kt+1)*64 + j*ASTR + 4);
        f16x8 h;
        #pragma unroll
        for (int jj = 0; jj < 8; ++jj) h[jj] = (f16)((jj < 4) ? v0[jj] : v1[jj-4]);
        ra[j] = h;
        rb[j] = *(const f16x8*)(Bb + (kt+1)*64 + (size_t)j * 32 * 256);
      }
    }
    #pragma unroll
    for (int kk = 0; kk < 2; ++kk){
      f16x8 af[4], bfr[4];
      #pragma unroll
      for (int mi = 0; mi < 4; ++mi){
        int row = wr*64 + mi*16 + (l & 15);
        int e = (row*64 + kk*32 + (l >> 4)*8) ^ ((row & 7) << 3);
        af[mi] = *(const f16x8*)&As[e];
      }
      #pragma unroll
      for (int ni = 0; ni < 4; ++ni){
        int row = wc*64 + ni*16 + (l & 15);
        int e = (row*64 + kk*32 + (l >> 4)*8) ^ ((row & 7) << 3);
        bfr[ni] = *(const f16x8*)&Bs[e];
      }
      #pragma unroll
      for (int mi = 0; mi < 4; ++mi)
        #pragma unroll
        for (int ni = 0; ni < 4; ++ni)
          acc[mi][ni] = mfma16(af[mi], bfr[ni], acc[mi][ni]);
    }
    __syncthreads();
  }
  const size_t m0 = (size_t)mt * 128;
  #pragma unroll
  for (int mi = 0; mi < 4; ++mi){
    #pragma unroll
    for (int ni = 0; ni < 4; ++ni){
      int col = n0 + wc*64 + ni*16 + (l & 15);
      size_t row = m0 + wr*64 + mi*16 + ((l >> 4) * 4);
      #pragma unroll
      for (int j = 0; j < 4; ++j)
        C[(row + j) * 1792 + col] = (f16)acc[mi][ni][j];
    }
  }
}

// ---------- recurrent kernel: 64 blocks x 16 rows, 1024 threads (16 waves) ----------
// wave w computes qg cols [w*64,(w+1)*64) in the MFMA phase, and owns batch row
// (r0+w) for the scores+GRU phase. 2 barriers per step.
__global__ __launch_bounds__(1024, 1) void recurrent_kernel(
    const f16* __restrict__ P, const f16* __restrict__ WsrT,
    const float* __restrict__ bias, const float* __restrict__ Lk,
    float* __restrict__ state, float* __restrict__ out,
    int t0, int nsteps)
{
  __shared__ float qg[16*1026];     // [16 rows][1024 cols] (query | gs), pad 2
  __shared__ float stf[16*260];     // fp32 state

  const int tid = threadIdx.x;
  const int l = tid & 63, w = tid >> 6;          // 16 waves
  const int r0 = blockIdx.x * 16;
  const int arow = l & 15, agrp = l >> 4;        // MFMA fragment mapping
  const int c4 = l * 4;                          // 4 cols per lane (scores/GRU)
  const int gb = r0 + w;                         // this wave's batch row

  const f32x4 rbias = *(const f32x4*)(bias + c4);
  const f32x4 rlk   = *(const f32x4*)(Lk + c4);

  *(f32x4*)&stf[w*260 + c4] = *(const f32x4*)(state + (size_t)gb*256 + c4);
  __syncthreads();

  const f16* wbase = WsrT + ((size_t)(w*64 + arow))*256 + agrp*8;

  for (int i = 0; i < nsteps; ++i){
    const int t = t0 + i;
    const f16* pt  = P + ((size_t)(i+2)*1024 + gb)*1792;
    const f16* pm1 = P + ((size_t)(i+1)*1024 + gb)*1792;
    const f16* pm2 = P + ((size_t)(i+0)*1024 + gb)*1792;

    // ---- cold prefetch: first touch of slab t (HBM); completes under qg phase ----
    const f16x4 e2  = *(const f16x4*)(pt + c4);
    const f16x4 gU  = *(const f16x4*)(pt +  256 + c4);
    const f16x4 gR  = *(const f16x4*)(pt +  512 + c4);
    const f16x4 gC  = *(const f16x4*)(pt +  768 + c4);
    const f16x4 gNU = *(const f16x4*)(pt + 1024 + c4);
    const f16x4 gNR = *(const f16x4*)(pt + 1280 + c4);
    const f16x4 gNC = *(const f16x4*)(pt + 1536 + c4);

    // ---- A-fragments: fp32 state -> fp16 ----
    f16x8 av[8];
    #pragma unroll
    for (int kt = 0; kt < 8; ++kt){
      const float* sp = &stf[arow*260 + kt*32 + agrp*8];
      f32x4 v0 = *(const f32x4*)sp;
      f32x4 v1 = *(const f32x4*)(sp + 4);
      f16x8 h;
      #pragma unroll
      for (int j = 0; j < 8; ++j) h[j] = (f16)((j < 4) ? v0[j] : v1[j-4]);
      av[kt] = h;
    }

    // ---- qg cols [w*64,(w+1)*64): 4 col-tiles, 2-kt-deep weight pipeline ----
    f32x4 acc[4];
    #pragma unroll
    for (int c = 0; c < 4; ++c) acc[c] = (f32x4){0.f,0.f,0.f,0.f};
    f16x8 wb0[4], wb1[4];
    #pragma unroll
    for (int c = 0; c < 4; ++c) wb0[c] = *(const f16x8*)(wbase + c*16*256);
    #pragma unroll
    for (int c = 0; c < 4; ++c) wb1[c] = *(const f16x8*)(wbase + c*16*256 + 32);
    #pragma unroll
    for (int kt = 0; kt < 8; ++kt){
      f16x8 cur[4];
      #pragma unroll
      for (int c = 0; c < 4; ++c) cur[c] = (kt & 1) ? wb1[c] : wb0[c];
      if (kt < 6){
        #pragma unroll
        for (int c = 0; c < 4; ++c){
          f16x8 nx = *(const f16x8*)(wbase + c*16*256 + (kt+2)*32);
          if (kt & 1) wb1[c] = nx; else wb0[c] = nx;
        }
      }
      #pragma unroll
      for (int c = 0; c < 4; ++c) acc[c] = mfma16(av[kt], cur[c], acc[c]);
    }
    #pragma unroll
    for (int c = 0; c < 4; ++c){
      #pragma unroll
      for (int j = 0; j < 4; ++j)
        qg[(agrp*4 + j)*1026 + w*64 + c*16 + arow] = acc[c][j];
    }
    __syncthreads();

    // ---- warm loads (slabs t-1,t-2: L2/L3-resident), hide under scores math ----
    const f16x4 e1  = *(const f16x4*)(pm1 + c4);
    const f16x4 e0  = *(const f16x4*)(pm2 + c4);
    const f16x4 m1U = *(const f16x4*)(pm1 +  256 + c4);
    const f16x4 m1R = *(const f16x4*)(pm1 +  512 + c4);
    const f16x4 m1C = *(const f16x4*)(pm1 +  768 + c4);
    const f16x4 m2U = *(const f16x4*)(pm2 +  256 + c4);
    const f16x4 m2R = *(const f16x4*)(pm2 +  512 + c4);
    const f16x4 m2C = *(const f16x4*)(pm2 +  768 + c4);

    // ---- scores + softmax: wave w owns row w; all lanes end with the probs ----
    const f32x4 q = *(const f32x4*)&qg[w*1026 + c4];
    float s0 = 0.f, s1 = 0.f, s2 = 0.f;
    #pragma unroll
    for (int j = 0; j < 4; ++j){
      const float qb = q[j] + rbias[j];
      s0 += tanh_f((float)e0[j] + qb) * rlk[j];
      s1 += tanh_f((float)e1[j] + qb) * rlk[j];
      s2 += tanh_f((float)e2[j] + qb) * rlk[j];
    }
    #pragma unroll
    for (int off = 32; off; off >>= 1){
      s0 += __shfl_xor(s0, off);
      s1 += __shfl_xor(s1, off);
      s2 += __shfl_xor(s2, off);
    }
    const float mx = fmaxf(fmaxf(s0, s1), s2);
    const float x0 = __expf(s0 - mx), x1 = __expf(s1 - mx), x2 = __expf(s2 - mx);
    const float inv = 1.0f / (x0 + x1 + x2);
    const float p0 = x0*inv, p1 = x1*inv, p2 = x2*inv;

    // ---- GRU elementwise + state update (row w, 4 cols/lane) ----
    const f32x4 qu = *(const f32x4*)&qg[w*1026 + 256 + c4];
    const f32x4 qr = *(const f32x4*)&qg[w*1026 + 512 + c4];
    const f32x4 qc = *(const f32x4*)&qg[w*1026 + 768 + c4];
    const f32x4 so = *(const f32x4*)&stf[w*260 + c4];
    f32x4 sn;
    #pragma unroll
    for (int j = 0; j < 4; ++j){
      const float geu = p2*(float)gU[j] + p1*(float)m1U[j] + p0*(float)m2U[j];
      const float ger = p2*(float)gR[j] + p1*(float)m1R[j] + p0*(float)m2R[j];
      const float gec = p2*(float)gC[j] + p1*(float)m1C[j] + p0*(float)m2C[j];
      const float up   = sigmoid_f(qu[j] + geu + (float)gNU[j]);
      const float rp   = sigmoid_f(qr[j] + ger + (float)gNR[j]);
      const float cand = tanh_f(rp*qc[j] + gec + (float)gNC[j]);
      sn[j] = (1.0f - up)*so[j] + up*cand;
    }
    *(f32x4*)&stf[w*260 + c4] = sn;
    if (t == 255) *(f32x4*)(out + (size_t)gb*256 + c4) = sn;
    __syncthreads();
  }

  *(f32x4*)(state + (size_t)gb*256 + c4) = *(const f32x4*)&stf[w*260 + c4];
}

// ---------------------------------- launch ----------------------------------
extern "C" void kernel_launch(void* const* d_in, const int* in_sizes, int n_in,
                              void* d_out, int out_size, void* d_ws, size_t ws_size,
                              hipStream_t stream)
{
  const float* X  = (const float*)d_in[0];
  const float* EK = (const float*)d_in[1];
  const float* SK = (const float*)d_in[2];
  const float* BI = (const float*)d_in[3];
  const float* LK = (const float*)d_in[4];
  const float* RS = (const float*)d_in[5];
  const float* RE = (const float*)d_in[6];
  const float* NW = (const float*)d_in[7];
  float* out = (float*)d_out;
  char* ws = (char*)d_ws;

  const size_t slabB = 1024ull * 1792ull * 2ull;           // 3,670,016 B
  const size_t wB = 917504ull + 524288ull + 1048576ull;
  int CT = 4;
  if      (ws_size >= 258ull*slabB + wB) CT = 256;
  else if (ws_size >= 130ull*slabB + wB) CT = 128;
  else if (ws_size >=  66ull*slabB + wB) CT = 64;
  else if (ws_size >=  34ull*slabB + wB) CT = 32;
  else if (ws_size >=  18ull*slabB + wB) CT = 16;
  else if (ws_size >=  10ull*slabB + wB) CT = 8;

  f16* P = (f16*)ws;
  size_t poff = (size_t)(CT + 2) * slabB;
  f16* WcatT = (f16*)(ws + poff);
  f16* WsrT  = (f16*)(ws + poff + 917504ull);
  float* state = (float*)(ws + poff + 917504ull + 524288ull);

  hipMemsetAsync(state, 0, 1048576ull, stream);
  hipMemsetAsync(P, 0, 2ull*slabB, stream);                // zero "virtual" slabs t=-2,-1
  cast_w_kernel<<<2816, 256, 0, stream>>>(EK, RE, NW, SK, RS, WcatT, WsrT);

  const int nch = 256 / CT;
  for (int c = 0; c < nch; ++c){
    const int t0 = c * CT;
    const int t_start  = (c == 0) ? 0 : (t0 - 2);
    const int slab_off = (c == 0) ? 2 : 0;
    const int Mtiles = (((c == 0) ? CT : (CT + 2)) * 1024) / 128;
    gemm_f16_kernel<<<Mtiles * 14, 256, 0, stream>>>(
        X, WcatT, P + (size_t)slab_off * 1024 * 1792, Mtiles, t_start);
    recurrent_kernel<<<64, 1024, 0, stream>>>(P, WsrT, BI, LK, state, out, t0, CT);
  }
}

// Round 5
// 4028.520 us; speedup vs baseline: 1.8361x; 1.0002x over previous
//
#include <hip/hip_runtime.h>

// AttentionRNN: B=1024, T=256, U=256.
//  P[t][b][0:1792) = x_t[b] @ [Wemb | Wre | Wnew]   (fp16 MFMA GEMM, chunked over T)
//  per step: qg = state @ [Wsk | Wrs] (fp16 MFMA), then scores/softmax/GRU.
//  64 blocks x 16 rows x 16 waves; wave w owns batch row r0+w (state in VGPRs).
//  Weights are FRAGMENT-PACKED (WsrF[w][c][kt][lane][8]) so every B-frag load
//  is a coalesced 1KB instruction. State f16 copy lives in fragment-major LDS.

typedef unsigned short u16;
typedef _Float16 f16;
typedef _Float16 f16x8 __attribute__((ext_vector_type(8)));
typedef _Float16 f16x4 __attribute__((ext_vector_type(4)));
typedef float f32x4 __attribute__((ext_vector_type(4)));

static __device__ __forceinline__ f32x4 mfma16(f16x8 a, f16x8 b, f32x4 c){
  return __builtin_amdgcn_mfma_f32_16x16x32_f16(a, b, c, 0, 0, 0);
}
static __device__ __forceinline__ float sigmoid_f(float x){
  return 1.0f / (1.0f + __expf(-x));
}
static __device__ __forceinline__ float tanh_f(float x){
  float e = __expf(2.0f * x);
  return 1.0f - 2.0f / (e + 1.0f);   // stable: -inf -> -1, +inf -> 1
}

// ------------- cast weights to fp16 -------------
// WcatT rows: [0,256) Wemb^T, [256,1024) Wre^T, [1024,1792) Wnew^T   (N x K row-major)
// WsrF: fragment-packed [w16][c4][kt8][lane64][e8]:
//   col = w*64 + c*16 + (lane&15), k = kt*32 + (lane>>4)*8 + e
__global__ void cast_w_kernel(const float* __restrict__ EK, const float* __restrict__ RE,
    const float* __restrict__ NW, const float* __restrict__ SK, const float* __restrict__ RS,
    f16* __restrict__ WcatT, f16* __restrict__ WsrF){
  int tid = blockIdx.x * 256 + threadIdx.x;
  if (tid < 458752){
    int n = tid >> 8, k = tid & 255;
    float v;
    if (n < 256)       v = EK[k*256 + n];
    else if (n < 1024) v = RE[k*768 + (n-256)];
    else               v = NW[k*768 + (n-1024)];
    WcatT[n*256 + k] = (f16)v;
  } else {
    int idx = tid - 458752;            // 0..262143
    int e    = idx & 7;
    int lane = (idx >> 3) & 63;
    int kt   = (idx >> 9) & 7;
    int c    = (idx >> 12) & 3;
    int w    = idx >> 14;              // 0..15
    int col  = w*64 + c*16 + (lane & 15);
    int k    = kt*32 + ((lane >> 4) & 3)*8 + e;
    float v = (col < 256) ? SK[k*256 + col] : RS[k*768 + (col-256)];
    WsrF[idx] = (f16)v;
  }
}

// ---- GEMM: C[r=tsl*1024+b][0:1792) = X[b][t_start+tsl][:] @ WcatT^T ----
__global__ __launch_bounds__(256, 2) void gemm_f16_kernel(
    const float* __restrict__ X, const f16* __restrict__ Bm,
    f16* __restrict__ C, int Mtiles, int t_start)
{
  __shared__ f16 As[128*64];
  __shared__ f16 Bs[128*64];
  const int NT = 14;
  const int nwg = Mtiles * NT;
  int bid = blockIdx.x, wg = bid;
  if ((nwg & 7) == 0){ int cpx = nwg >> 3; wg = (bid & 7) * cpx + (bid >> 3); }
  const int mt = wg / NT, nt = wg % NT;
  const int tsl = mt >> 3;
  const int b0  = (mt & 7) * 128;
  const int t   = t_start + tsl;
  const int n0  = nt * 128;
  const int tid = threadIdx.x;
  const int l = tid & 63, wid = tid >> 6;
  const int wr = wid >> 1, wc = wid & 1;
  const int srow = tid >> 3;
  const int scol = (tid & 7) * 8;

  const size_t ASTR = 32ull * 65536ull;
  const float* Ab = X + ((size_t)(b0 + srow) * 256 + t) * 256 + scol;
  const f16*   Bb = Bm + ((size_t)(n0 + srow)) * 256 + scol;

  f16x8 ra[4], rb[4];
  #pragma unroll
  for (int j = 0; j < 4; ++j){
    f32x4 v0 = *(const f32x4*)(Ab + j*ASTR);
    f32x4 v1 = *(const f32x4*)(Ab + j*ASTR + 4);
    f16x8 h;
    #pragma unroll
    for (int jj = 0; jj < 8; ++jj) h[jj] = (f16)((jj < 4) ? v0[jj] : v1[jj-4]);
    ra[j] = h;
    rb[j] = *(const f16x8*)(Bb + (size_t)j * 32 * 256);
  }

  f32x4 acc[4][4];
  #pragma unroll
  for (int mi = 0; mi < 4; ++mi)
    #pragma unroll
    for (int ni = 0; ni < 4; ++ni)
      acc[mi][ni] = (f32x4){0.f,0.f,0.f,0.f};

  for (int kt = 0; kt < 4; ++kt){
    #pragma unroll
    for (int j = 0; j < 4; ++j){
      int row = srow + j*32;
      int e = (row*64 + scol) ^ ((row & 7) << 3);
      *(f16x8*)&As[e] = ra[j];
      *(f16x8*)&Bs[e] = rb[j];
    }
    __syncthreads();
    if (kt < 3){
      #pragma unroll
      for (int j = 0; j < 4; ++j){
        f32x4 v0 = *(const f32x4*)(Ab + (kt+1)*64 + j*ASTR);
        f32x4 v1 = *(const f32x4*)(Ab + (kt+1)*64 + j*ASTR + 4);
        f16x8 h;
        #pragma unroll
        for (int jj = 0; jj < 8; ++jj) h[jj] = (f16)((jj < 4) ? v0[jj] : v1[jj-4]);
        ra[j] = h;
        rb[j] = *(const f16x8*)(Bb + (kt+1)*64 + (size_t)j * 32 * 256);
      }
    }
    #pragma unroll
    for (int kk = 0; kk < 2; ++kk){
      f16x8 af[4], bfr[4];
      #pragma unroll
      for (int mi = 0; mi < 4; ++mi){
        int row = wr*64 + mi*16 + (l & 15);
        int e = (row*64 + kk*32 + (l >> 4)*8) ^ ((row & 7) << 3);
        af[mi] = *(const f16x8*)&As[e];
      }
      #pragma unroll
      for (int ni = 0; ni < 4; ++ni){
        int row = wc*64 + ni*16 + (l & 15);
        int e = (row*64 + kk*32 + (l >> 4)*8) ^ ((row & 7) << 3);
        bfr[ni] = *(const f16x8*)&Bs[e];
      }
      #pragma unroll
      for (int mi = 0; mi < 4; ++mi)
        #pragma unroll
        for (int ni = 0; ni < 4; ++ni)
          acc[mi][ni] = mfma16(af[mi], bfr[ni], acc[mi][ni]);
    }
    __syncthreads();
  }
  const size_t m0 = (size_t)mt * 128;
  #pragma unroll
  for (int mi = 0; mi < 4; ++mi){
    #pragma unroll
    for (int ni = 0; ni < 4; ++ni){
      int col = n0 + wc*64 + ni*16 + (l & 15);
      size_t row = m0 + wr*64 + mi*16 + ((l >> 4) * 4);
      #pragma unroll
      for (int j = 0; j < 4; ++j)
        C[(row + j) * 1792 + col] = (f16)acc[mi][ni][j];
    }
  }
}

// ---------- recurrent kernel: 64 blocks x 16 rows, 1024 threads (16 waves) ----------
__global__ __launch_bounds__(1024, 1) void recurrent_kernel(
    const f16* __restrict__ P, const f16* __restrict__ WsrF,
    const float* __restrict__ bias, const float* __restrict__ Lk,
    float* __restrict__ state, float* __restrict__ out,
    int t0, int nsteps)
{
  __shared__ float qg[16*1026];     // [16 rows][1024 cols] (query | gs), pad 2
  __shared__ f16  stA[8*520];       // state f16, fragment-major [kt][lane][8] + pad

  const int tid = threadIdx.x;
  const int l = tid & 63, w = tid >> 6;          // 16 waves
  const int r0 = blockIdx.x * 16;
  const int arow = l & 15, agrp = l >> 4;        // MFMA fragment mapping
  const int c4 = l * 4;                          // 4 cols per lane (scores/GRU)
  const int gb = r0 + w;                         // this wave's batch row

  const f32x4 rbias = *(const f32x4*)(bias + c4);
  const f32x4 rlk   = *(const f32x4*)(Lk + c4);

  // fp32 state lives in registers: wave w owns row w, 4 cols per lane
  f32x4 sn = *(const f32x4*)(state + (size_t)gb*256 + c4);

  // stA write slot for this lane: row w, k = c4..c4+3
  f16* const sa_wp = &stA[(l >> 3)*520 + ((((l >> 1) & 3) << 4) + w)*8 + (l & 1)*4];
  {
    f16x4 h;
    #pragma unroll
    for (int j = 0; j < 4; ++j) h[j] = (f16)sn[j];
    *(f16x4*)sa_wp = h;
  }
  __syncthreads();

  const f16* const wb = WsrF + (size_t)w * 16384;   // w * 4*8*64*8

  for (int i = 0; i < nsteps; ++i){
    const int t = t0 + i;
    const f16* pt  = P + ((size_t)(i+2)*1024 + gb)*1792;
    const f16* pm1 = P + ((size_t)(i+1)*1024 + gb)*1792;
    const f16* pm2 = P + ((size_t)(i+0)*1024 + gb)*1792;

    // ---- cold prefetch: first touch of slab t (HBM); completes under qg phase ----
    const f16x4 e2  = *(const f16x4*)(pt + c4);
    const f16x4 gU  = *(const f16x4*)(pt +  256 + c4);
    const f16x4 gR  = *(const f16x4*)(pt +  512 + c4);
    const f16x4 gC  = *(const f16x4*)(pt +  768 + c4);
    const f16x4 gNU = *(const f16x4*)(pt + 1024 + c4);
    const f16x4 gNR = *(const f16x4*)(pt + 1280 + c4);
    const f16x4 gNC = *(const f16x4*)(pt + 1536 + c4);

    // ---- A-fragments straight from fragment-major LDS (conflict-free b128) ----
    f16x8 av[8];
    #pragma unroll
    for (int kt = 0; kt < 8; ++kt)
      av[kt] = *(const f16x8*)&stA[kt*520 + l*8];

    // ---- qg cols [w*64,(w+1)*64): 4 col-tiles, coalesced frag loads, 2-deep pipe ----
    f32x4 acc[4];
    #pragma unroll
    for (int c = 0; c < 4; ++c) acc[c] = (f32x4){0.f,0.f,0.f,0.f};
    f16x8 wb0[4], wb1[4];
    #pragma unroll
    for (int c = 0; c < 4; ++c) wb0[c] = *(const f16x8*)(wb + ((c*8 + 0)*64 + l)*8);
    #pragma unroll
    for (int c = 0; c < 4; ++c) wb1[c] = *(const f16x8*)(wb + ((c*8 + 1)*64 + l)*8);
    #pragma unroll
    for (int kt = 0; kt < 8; ++kt){
      f16x8 cur[4];
      #pragma unroll
      for (int c = 0; c < 4; ++c) cur[c] = (kt & 1) ? wb1[c] : wb0[c];
      if (kt < 6){
        #pragma unroll
        for (int c = 0; c < 4; ++c){
          f16x8 nx = *(const f16x8*)(wb + ((c*8 + kt + 2)*64 + l)*8);
          if (kt & 1) wb1[c] = nx; else wb0[c] = nx;
        }
      }
      #pragma unroll
      for (int c = 0; c < 4; ++c) acc[c] = mfma16(av[kt], cur[c], acc[c]);
    }
    #pragma unroll
    for (int c = 0; c < 4; ++c){
      #pragma unroll
      for (int j = 0; j < 4; ++j)
        qg[(agrp*4 + j)*1026 + w*64 + c*16 + arow] = acc[c][j];
    }
    __syncthreads();

    // ---- warm loads (slabs t-1,t-2 rows touched 1-2 steps ago: L2-resident) ----
    const f16x4 e1  = *(const f16x4*)(pm1 + c4);
    const f16x4 e0  = *(const f16x4*)(pm2 + c4);
    const f16x4 m1U = *(const f16x4*)(pm1 +  256 + c4);
    const f16x4 m1R = *(const f16x4*)(pm1 +  512 + c4);
    const f16x4 m1C = *(const f16x4*)(pm1 +  768 + c4);
    const f16x4 m2U = *(const f16x4*)(pm2 +  256 + c4);
    const f16x4 m2R = *(const f16x4*)(pm2 +  512 + c4);
    const f16x4 m2C = *(const f16x4*)(pm2 +  768 + c4);

    // ---- scores + softmax: wave w owns row w; all lanes end with the probs ----
    const f32x4 q = *(const f32x4*)&qg[w*1026 + c4];
    float s0 = 0.f, s1 = 0.f, s2 = 0.f;
    #pragma unroll
    for (int j = 0; j < 4; ++j){
      const float qb = q[j] + rbias[j];
      s0 += tanh_f((float)e0[j] + qb) * rlk[j];
      s1 += tanh_f((float)e1[j] + qb) * rlk[j];
      s2 += tanh_f((float)e2[j] + qb) * rlk[j];
    }
    #pragma unroll
    for (int off = 32; off; off >>= 1){
      s0 += __shfl_xor(s0, off);
      s1 += __shfl_xor(s1, off);
      s2 += __shfl_xor(s2, off);
    }
    const float mx = fmaxf(fmaxf(s0, s1), s2);
    const float x0 = __expf(s0 - mx), x1 = __expf(s1 - mx), x2 = __expf(s2 - mx);
    const float inv = 1.0f / (x0 + x1 + x2);
    const float p0 = x0*inv, p1 = x1*inv, p2 = x2*inv;

    // ---- GRU elementwise + state update (row w, 4 cols/lane, state in regs) ----
    const f32x4 qu = *(const f32x4*)&qg[w*1026 + 256 + c4];
    const f32x4 qr = *(const f32x4*)&qg[w*1026 + 512 + c4];
    const f32x4 qc = *(const f32x4*)&qg[w*1026 + 768 + c4];
    f32x4 sold = sn;
    #pragma unroll
    for (int j = 0; j < 4; ++j){
      const float geu = p2*(float)gU[j] + p1*(float)m1U[j] + p0*(float)m2U[j];
      const float ger = p2*(float)gR[j] + p1*(float)m1R[j] + p0*(float)m2R[j];
      const float gec = p2*(float)gC[j] + p1*(float)m1C[j] + p0*(float)m2C[j];
      const float up   = sigmoid_f(qu[j] + geu + (float)gNU[j]);
      const float rp   = sigmoid_f(qr[j] + ger + (float)gNR[j]);
      const float cand = tanh_f(rp*qc[j] + gec + (float)gNC[j]);
      sn[j] = (1.0f - up)*sold[j] + up*cand;
    }
    {
      f16x4 h;
      #pragma unroll
      for (int j = 0; j < 4; ++j) h[j] = (f16)sn[j];
      *(f16x4*)sa_wp = h;
    }
    if (t == 255) *(f32x4*)(out + (size_t)gb*256 + c4) = sn;
    __syncthreads();
  }

  *(f32x4*)(state + (size_t)gb*256 + c4) = sn;
}

// ---------------------------------- launch ----------------------------------
extern "C" void kernel_launch(void* const* d_in, const int* in_sizes, int n_in,
                              void* d_out, int out_size, void* d_ws, size_t ws_size,
                              hipStream_t stream)
{
  const float* X  = (const float*)d_in[0];
  const float* EK = (const float*)d_in[1];
  const float* SK = (const float*)d_in[2];
  const float* BI = (const float*)d_in[3];
  const float* LK = (const float*)d_in[4];
  const float* RS = (const float*)d_in[5];
  const float* RE = (const float*)d_in[6];
  const float* NW = (const float*)d_in[7];
  float* out = (float*)d_out;
  char* ws = (char*)d_ws;

  const size_t slabB = 1024ull * 1792ull * 2ull;           // 3,670,016 B
  const size_t wB = 917504ull + 524288ull + 1048576ull;
  int CT = 4;
  if      (ws_size >= 258ull*slabB + wB) CT = 256;
  else if (ws_size >= 130ull*slabB + wB) CT = 128;
  else if (ws_size >=  66ull*slabB + wB) CT = 64;
  else if (ws_size >=  34ull*slabB + wB) CT = 32;
  else if (ws_size >=  18ull*slabB + wB) CT = 16;
  else if (ws_size >=  10ull*slabB + wB) CT = 8;

  f16* P = (f16*)ws;
  size_t poff = (size_t)(CT + 2) * slabB;
  f16* WcatT = (f16*)(ws + poff);
  f16* WsrF  = (f16*)(ws + poff + 917504ull);
  float* state = (float*)(ws + poff + 917504ull + 524288ull);

  hipMemsetAsync(state, 0, 1048576ull, stream);
  hipMemsetAsync(P, 0, 2ull*slabB, stream);                // zero "virtual" slabs t=-2,-1
  cast_w_kernel<<<2816, 256, 0, stream>>>(EK, RE, NW, SK, RS, WcatT, WsrF);

  const int nch = 256 / CT;
  for (int c = 0; c < nch; ++c){
    const int t0 = c * CT;
    const int t_start  = (c == 0) ? 0 : (t0 - 2);
    const int slab_off = (c == 0) ? 2 : 0;
    const int Mtiles = (((c == 0) ? CT : (CT + 2)) * 1024) / 128;
    gemm_f16_kernel<<<Mtiles * 14, 256, 0, stream>>>(
        X, WcatT, P + (size_t)slab_off * 1024 * 1792, Mtiles, t_start);
    recurrent_kernel<<<64, 1024, 0, stream>>>(P, WsrF, BI, LK, state, out, t0, CT);
  }
}